// Round 4
// baseline (735.943 us; speedup 1.0000x reference)
//
#include <hip/hip_runtime.h>
#include <hip/hip_bf16.h>

#define TPB 512

typedef _Float16 half8 __attribute__((ext_vector_type(8)));
typedef float    f32x4 __attribute__((ext_vector_type(4)));

constexpr int kDIM   = 256;
constexpr int kP     = 32;   // patch size
constexpr int kPOS   = 25;
constexpr int kRPE   = 51;
constexpr float kSCALE = 0.17677669529663687f; // 32^-0.5

// ---- d_ws packed-weight layout (in _Float16 units) ----
constexpr size_t WQ_HI  = 0;        // 65536 halves (16nt * 8k0 * 64 * 8)
constexpr size_t WQ_LO  = 65536;
constexpr size_t WKV_HI = 131072;   // 131072 halves (32nt * 8k0 * 64 * 8)
constexpr size_t WKV_LO = 262144;
constexpr size_t WO_HI  = 393216;   // 65536 halves
constexpr size_t WO_LO  = 458752;
constexpr size_t WS_NEED_BYTES = 1048576;

// ---- LDS arena (bytes); total 149,632 <= 160 KiB ----
constexpr int ARENA_BYTES = 149632;

//==========================================================================
// Weight pack: W (row-major [K][C]) -> fragment-linear fp16 hi/lo.
// B-frag for tile (nt,k0), lane l, elem j = W[k0*32 + (l>>4)*8 + j][nt*16 + (l&15)]
// stored at dst[((nt*8+k0)*64 + l)*8 + j].
//==========================================================================
__global__ void pack_weights(const float* __restrict__ Wq,
                             const float* __restrict__ Wkv,
                             const float* __restrict__ Wo,
                             _Float16* __restrict__ ws)
{
    int T = blockIdx.x * 256 + threadIdx.x;   // 0..32767
    const float* W;
    _Float16* dh;
    _Float16* dl;
    int C, i;
    if (T < 8192) {
        W = Wq;  C = 256; i = T;         dh = ws + WQ_HI;  dl = ws + WQ_LO;
    } else if (T < 24576) {
        W = Wkv; C = 512; i = T - 8192;  dh = ws + WKV_HI; dl = ws + WKV_LO;
    } else {
        W = Wo;  C = 256; i = T - 24576; dh = ws + WO_HI;  dl = ws + WO_LO;
    }
    int nt = i >> 9;
    int k0 = (i >> 6) & 7;
    int l  = i & 63;
    int kb = k0 * 32 + ((l >> 4) << 3);
    int n  = nt * 16 + (l & 15);
    half8 H, L;
    #pragma unroll
    for (int j = 0; j < 8; ++j) {
        float w = W[(size_t)(kb + j) * C + n];
        _Float16 h = (_Float16)w;
        H[j] = h;
        L[j] = (_Float16)(w - (float)h);
    }
    *reinterpret_cast<half8*>(dh + (size_t)i * 8) = H;
    *reinterpret_cast<half8*>(dl + (size_t)i * 8) = L;
}

//==========================================================================
// Fused per-patch kernel: MFMA projections + fp32 VALU attention.
//==========================================================================
__global__ __launch_bounds__(TPB, 2)
void octree_attn_mfma(const float* __restrict__ q_data,
                      const float* __restrict__ kv_data,
                      const int*   __restrict__ rel_pos,
                      const float* __restrict__ mask,
                      const float* __restrict__ bq,
                      const float* __restrict__ bkv,
                      const float* __restrict__ bo,
                      const float* __restrict__ rpe_table,
                      const _Float16* __restrict__ wsh,
                      float* __restrict__ out)
{
    __shared__ __align__(16) char arena[ARENA_BYTES];
    _Float16* XqF_hi  = (_Float16*)(arena);            // [0,16384)
    _Float16* XqF_lo  = (_Float16*)(arena + 16384);    // [16384,32768)
    _Float16* XkvF_hi = (_Float16*)(arena + 33280);    // [33280,49664)
    _Float16* XkvF_lo = (_Float16*)(arena + 49664);    // [49664,66048)
    float*    Qs      = (float*)   (arena + 33280);    // overlays XkvF after KV-proj, [32][260]
    float*    KVs     = (float*)   (arena + 66560);    // [32][516]
    unsigned char* rpl8 = (unsigned char*)(arena + 132608); // [32][100] u8
    float*    msk     = (float*)   (arena + 135808);   // [32][36]
    float*    rpe_t   = (float*)   (arena + 140416);   // [8][160]
    float*    bql     = (float*)   (arena + 145536);   // [256]
    float*    bkvl    = (float*)   (arena + 146560);   // [512]
    float*    bol     = (float*)   (arena + 148608);   // [256]
    _Float16* AOF_hi  = XqF_hi;                        // overlays XqF after Q-proj
    _Float16* AOF_lo  = XqF_lo;

    const int m    = blockIdx.x;
    const int tid  = threadIdx.x;
    const int wave = tid >> 6;
    const int lane = tid & 63;

    //---------------- stage + fp16 hi/lo split (coalesced) ----------------
    {
        const float* qsrc = q_data  + (size_t)m * kP * kDIM;
        const float* ksrc = kv_data + (size_t)m * kP * kDIM;
        #pragma unroll
        for (int rep = 0; rep < 2; ++rep) {
            int f = tid + rep * TPB;            // slot of 8 floats; 1024 slots
            int row = f >> 5;
            int b   = f & 31;
            int mt = row >> 4;
            int k0 = b >> 2;
            int kg = b & 3;
            int off = ((mt * 8 + k0) * 64 + ((kg << 4) | (row & 15))) * 8;
            float4 x0 = *reinterpret_cast<const float4*>(qsrc + f * 8);
            float4 x1 = *reinterpret_cast<const float4*>(qsrc + f * 8 + 4);
            float xs[8] = {x0.x, x0.y, x0.z, x0.w, x1.x, x1.y, x1.z, x1.w};
            half8 H, L;
            #pragma unroll
            for (int j = 0; j < 8; ++j) {
                _Float16 h = (_Float16)xs[j];
                H[j] = h;
                L[j] = (_Float16)(xs[j] - (float)h);
            }
            *reinterpret_cast<half8*>(XqF_hi + off) = H;
            *reinterpret_cast<half8*>(XqF_lo + off) = L;
            float4 y0 = *reinterpret_cast<const float4*>(ksrc + f * 8);
            float4 y1 = *reinterpret_cast<const float4*>(ksrc + f * 8 + 4);
            float ys[8] = {y0.x, y0.y, y0.z, y0.w, y1.x, y1.y, y1.z, y1.w};
            #pragma unroll
            for (int j = 0; j < 8; ++j) {
                _Float16 h = (_Float16)ys[j];
                H[j] = h;
                L[j] = (_Float16)(ys[j] - (float)h);
            }
            *reinterpret_cast<half8*>(XkvF_hi + off) = H;
            *reinterpret_cast<half8*>(XkvF_lo + off) = L;
        }
        // rel_pos -> clamped u8 (value+25 in 0..50)
        const int4* rsrc = reinterpret_cast<const int4*>(rel_pos + (size_t)m * kP * kP * 3);
        for (int f = tid; f < 768; f += TPB) {
            int4 v = rsrc[f];
            int idx = f * 4;
            int row = idx / 96;
            int col = idx % 96;
            uchar4 pk;
            pk.x = (unsigned char)(min(max(v.x, -kPOS), kPOS) + kPOS);
            pk.y = (unsigned char)(min(max(v.y, -kPOS), kPOS) + kPOS);
            pk.z = (unsigned char)(min(max(v.z, -kPOS), kPOS) + kPOS);
            pk.w = (unsigned char)(min(max(v.w, -kPOS), kPOS) + kPOS);
            *reinterpret_cast<uchar4*>(rpl8 + row * 100 + col) = pk;
        }
        const float4* msrc = reinterpret_cast<const float4*>(mask + (size_t)m * kP * kP);
        if (tid < 256) {
            int row = tid >> 3;
            int w   = tid & 7;
            *reinterpret_cast<float4*>(&msk[row * 36 + w * 4]) = msrc[tid];
        }
        for (int i = tid; i < 3 * kRPE * 8; i += TPB) {
            int idx = i >> 3;
            int h   = i & 7;                   // rpe_table (153,8) row-major
            rpe_t[h * 160 + idx] = rpe_table[i];
        }
        if (tid < 256) { bql[tid] = bq[tid]; bol[tid] = bo[tid]; }
        if (tid < 512) { bkvl[tid] = bkv[tid]; }
    }
    __syncthreads();

    //---------------- KV projection (MFMA): KV = Xkv @ Wkv + bkv ----------------
    // wave owns nt = 4w..4w+3 (of 32), both mt; 3-product fp16 split.
    {
        const _Float16* Bh = wsh + WKV_HI;
        const _Float16* Bl = wsh + WKV_LO;
        const int nt0 = wave * 4;
        f32x4 acc[2][4];
        #pragma unroll
        for (int a = 0; a < 2; ++a) {
            #pragma unroll
            for (int b = 0; b < 4; ++b) acc[a][b] = f32x4{0.f, 0.f, 0.f, 0.f};
        }
        #pragma unroll
        for (int k0 = 0; k0 < 8; ++k0) {
            half8 a0h = *reinterpret_cast<const half8*>(XkvF_hi + (k0 * 64 + lane) * 8);
            half8 a0l = *reinterpret_cast<const half8*>(XkvF_lo + (k0 * 64 + lane) * 8);
            half8 a1h = *reinterpret_cast<const half8*>(XkvF_hi + ((8 + k0) * 64 + lane) * 8);
            half8 a1l = *reinterpret_cast<const half8*>(XkvF_lo + ((8 + k0) * 64 + lane) * 8);
            #pragma unroll
            for (int ntl = 0; ntl < 4; ++ntl) {
                int nt = nt0 + ntl;
                half8 bh = *reinterpret_cast<const half8*>(Bh + ((size_t)(nt * 8 + k0) * 64 + lane) * 8);
                half8 bl = *reinterpret_cast<const half8*>(Bl + ((size_t)(nt * 8 + k0) * 64 + lane) * 8);
                acc[0][ntl] = __builtin_amdgcn_mfma_f32_16x16x32_f16(a0h, bh, acc[0][ntl], 0, 0, 0);
                acc[0][ntl] = __builtin_amdgcn_mfma_f32_16x16x32_f16(a0l, bh, acc[0][ntl], 0, 0, 0);
                acc[0][ntl] = __builtin_amdgcn_mfma_f32_16x16x32_f16(a0h, bl, acc[0][ntl], 0, 0, 0);
                acc[1][ntl] = __builtin_amdgcn_mfma_f32_16x16x32_f16(a1h, bh, acc[1][ntl], 0, 0, 0);
                acc[1][ntl] = __builtin_amdgcn_mfma_f32_16x16x32_f16(a1l, bh, acc[1][ntl], 0, 0, 0);
                acc[1][ntl] = __builtin_amdgcn_mfma_f32_16x16x32_f16(a1h, bl, acc[1][ntl], 0, 0, 0);
            }
        }
        #pragma unroll
        for (int ntl = 0; ntl < 4; ++ntl) {
            int col = (nt0 + ntl) * 16 + (lane & 15);
            float bv = bkvl[col];
            #pragma unroll
            for (int mt = 0; mt < 2; ++mt) {
                #pragma unroll
                for (int r = 0; r < 4; ++r) {
                    int row = mt * 16 + (lane >> 4) * 4 + r;
                    KVs[row * 516 + col] = acc[mt][ntl][r] + bv;
                }
            }
        }
    }
    __syncthreads();   // XkvF fully consumed -> region becomes Qs

    //---------------- Q projection (MFMA): Q = (Xq @ Wq + bq) * SCALE ----------------
    {
        const _Float16* Bh = wsh + WQ_HI;
        const _Float16* Bl = wsh + WQ_LO;
        const int nt0 = wave * 2;
        f32x4 acc[2][2];
        #pragma unroll
        for (int a = 0; a < 2; ++a) {
            #pragma unroll
            for (int b = 0; b < 2; ++b) acc[a][b] = f32x4{0.f, 0.f, 0.f, 0.f};
        }
        #pragma unroll
        for (int k0 = 0; k0 < 8; ++k0) {
            half8 a0h = *reinterpret_cast<const half8*>(XqF_hi + (k0 * 64 + lane) * 8);
            half8 a0l = *reinterpret_cast<const half8*>(XqF_lo + (k0 * 64 + lane) * 8);
            half8 a1h = *reinterpret_cast<const half8*>(XqF_hi + ((8 + k0) * 64 + lane) * 8);
            half8 a1l = *reinterpret_cast<const half8*>(XqF_lo + ((8 + k0) * 64 + lane) * 8);
            #pragma unroll
            for (int ntl = 0; ntl < 2; ++ntl) {
                int nt = nt0 + ntl;
                half8 bh = *reinterpret_cast<const half8*>(Bh + ((size_t)(nt * 8 + k0) * 64 + lane) * 8);
                half8 bl = *reinterpret_cast<const half8*>(Bl + ((size_t)(nt * 8 + k0) * 64 + lane) * 8);
                acc[0][ntl] = __builtin_amdgcn_mfma_f32_16x16x32_f16(a0h, bh, acc[0][ntl], 0, 0, 0);
                acc[0][ntl] = __builtin_amdgcn_mfma_f32_16x16x32_f16(a0l, bh, acc[0][ntl], 0, 0, 0);
                acc[0][ntl] = __builtin_amdgcn_mfma_f32_16x16x32_f16(a0h, bl, acc[0][ntl], 0, 0, 0);
                acc[1][ntl] = __builtin_amdgcn_mfma_f32_16x16x32_f16(a1h, bh, acc[1][ntl], 0, 0, 0);
                acc[1][ntl] = __builtin_amdgcn_mfma_f32_16x16x32_f16(a1l, bh, acc[1][ntl], 0, 0, 0);
                acc[1][ntl] = __builtin_amdgcn_mfma_f32_16x16x32_f16(a1h, bl, acc[1][ntl], 0, 0, 0);
            }
        }
        #pragma unroll
        for (int ntl = 0; ntl < 2; ++ntl) {
            int col = (nt0 + ntl) * 16 + (lane & 15);
            float bv = bql[col];
            #pragma unroll
            for (int mt = 0; mt < 2; ++mt) {
                #pragma unroll
                for (int r = 0; r < 4; ++r) {
                    int row = mt * 16 + (lane >> 4) * 4 + r;
                    Qs[row * 260 + col] = (acc[mt][ntl][r] + bv) * kSCALE;
                }
            }
        }
    }
    __syncthreads();   // Q, K, V ready

    //---------------- attention (fp32 VALU): one wave per head ----------------
    {
        const int h  = wave;
        const int ri = lane >> 3;   // rows ri + 8i
        const int ci = lane & 7;    // cols ci + 8j
        float s[4][4];
        #pragma unroll
        for (int i = 0; i < 4; ++i) {
            #pragma unroll
            for (int j = 0; j < 4; ++j) s[i][j] = 0.f;
        }

        #pragma unroll
        for (int db = 0; db < 8; ++db) {
            float4 qv[4], kv[4];
            #pragma unroll
            for (int i = 0; i < 4; ++i)
                qv[i] = *reinterpret_cast<const float4*>(&Qs[(ri + 8 * i) * 260 + h * 32 + db * 4]);
            #pragma unroll
            for (int j = 0; j < 4; ++j)
                kv[j] = *reinterpret_cast<const float4*>(&KVs[(ci + 8 * j) * 516 + h * 32 + db * 4]);
            #pragma unroll
            for (int i = 0; i < 4; ++i) {
                #pragma unroll
                for (int j = 0; j < 4; ++j) {
                    s[i][j] = fmaf(qv[i].x, kv[j].x, s[i][j]);
                    s[i][j] = fmaf(qv[i].y, kv[j].y, s[i][j]);
                    s[i][j] = fmaf(qv[i].z, kv[j].z, s[i][j]);
                    s[i][j] = fmaf(qv[i].w, kv[j].w, s[i][j]);
                }
            }
        }

        // rpe bias (u8-staged) + mask
        #pragma unroll
        for (int i = 0; i < 4; ++i) {
            #pragma unroll
            for (int j = 0; j < 4; ++j) {
                int r = ri + 8 * i;
                int c = ci + 8 * j;
                int base = r * 100 + c * 3;
                int p0 = rpl8[base + 0];
                int p1 = rpl8[base + 1];
                int p2 = rpl8[base + 2];
                float bias = rpe_t[h * 160 + p0]
                           + rpe_t[h * 160 + 51 + p1]
                           + rpe_t[h * 160 + 102 + p2];
                s[i][j] += bias + msk[r * 36 + c];
            }
        }

        // softmax over 32 cols (4 regs x 8 ci-lanes)
        #pragma unroll
        for (int i = 0; i < 4; ++i) {
            float mx = fmaxf(fmaxf(s[i][0], s[i][1]), fmaxf(s[i][2], s[i][3]));
            mx = fmaxf(mx, __shfl_xor(mx, 1));
            mx = fmaxf(mx, __shfl_xor(mx, 2));
            mx = fmaxf(mx, __shfl_xor(mx, 4));
            float e0 = __expf(s[i][0] - mx);
            float e1 = __expf(s[i][1] - mx);
            float e2 = __expf(s[i][2] - mx);
            float e3 = __expf(s[i][3] - mx);
            float sum = e0 + e1 + e2 + e3;
            sum += __shfl_xor(sum, 1);
            sum += __shfl_xor(sum, 2);
            sum += __shfl_xor(sum, 4);
            float inv = 1.0f / sum;
            s[i][0] = e0 * inv;
            s[i][1] = e1 * inv;
            s[i][2] = e2 * inv;
            s[i][3] = e3 * inv;
        }

        // P -> this head's own (now dead) Q columns
        #pragma unroll
        for (int i = 0; i < 4; ++i) {
            #pragma unroll
            for (int j = 0; j < 4; ++j)
                Qs[(ri + 8 * i) * 260 + h * 32 + ci + 8 * j] = s[i][j];
        }
        __syncthreads();

        // PV -> write directly as O-proj A-frags (hi/lo), overlaying dead XqF
        float o[4][4];
        #pragma unroll
        for (int i = 0; i < 4; ++i) {
            #pragma unroll
            for (int j = 0; j < 4; ++j) o[i][j] = 0.f;
        }
        #pragma unroll 4
        for (int c = 0; c < kP; ++c) {
            float pv[4], vv[4];
            #pragma unroll
            for (int i = 0; i < 4; ++i)
                pv[i] = Qs[(ri + 8 * i) * 260 + h * 32 + c];
            #pragma unroll
            for (int j = 0; j < 4; ++j)
                vv[j] = KVs[c * 516 + 256 + h * 32 + ci + 8 * j];
            #pragma unroll
            for (int i = 0; i < 4; ++i) {
                #pragma unroll
                for (int j = 0; j < 4; ++j)
                    o[i][j] = fmaf(pv[i], vv[j], o[i][j]);
            }
        }
        // frag position: row = ri+8i, k = h*32 + ci + 8j -> k0 = h, kg = j, elem = ci
        #pragma unroll
        for (int i = 0; i < 4; ++i) {
            int row = ri + 8 * i;
            int mt  = row >> 4;
            #pragma unroll
            for (int j = 0; j < 4; ++j) {
                int offv = ((mt * 8 + h) * 64 + ((j << 4) | (row & 15))) * 8 + ci;
                float val = o[i][j];
                _Float16 hh = (_Float16)val;
                AOF_hi[offv] = hh;
                AOF_lo[offv] = (_Float16)(val - (float)hh);
            }
        }
    }
    __syncthreads();   // AOF complete

    //---------------- output projection (MFMA): out = AO @ Wo + bo ----------------
    {
        const _Float16* Bh = wsh + WO_HI;
        const _Float16* Bl = wsh + WO_LO;
        const int nt0 = wave * 2;
        f32x4 acc[2][2];
        #pragma unroll
        for (int a = 0; a < 2; ++a) {
            #pragma unroll
            for (int b = 0; b < 2; ++b) acc[a][b] = f32x4{0.f, 0.f, 0.f, 0.f};
        }
        #pragma unroll
        for (int k0 = 0; k0 < 8; ++k0) {
            half8 a0h = *reinterpret_cast<const half8*>(AOF_hi + (k0 * 64 + lane) * 8);
            half8 a0l = *reinterpret_cast<const half8*>(AOF_lo + (k0 * 64 + lane) * 8);
            half8 a1h = *reinterpret_cast<const half8*>(AOF_hi + ((8 + k0) * 64 + lane) * 8);
            half8 a1l = *reinterpret_cast<const half8*>(AOF_lo + ((8 + k0) * 64 + lane) * 8);
            #pragma unroll
            for (int ntl = 0; ntl < 2; ++ntl) {
                int nt = nt0 + ntl;
                half8 bh = *reinterpret_cast<const half8*>(Bh + ((size_t)(nt * 8 + k0) * 64 + lane) * 8);
                half8 bl = *reinterpret_cast<const half8*>(Bl + ((size_t)(nt * 8 + k0) * 64 + lane) * 8);
                acc[0][ntl] = __builtin_amdgcn_mfma_f32_16x16x32_f16(a0h, bh, acc[0][ntl], 0, 0, 0);
                acc[0][ntl] = __builtin_amdgcn_mfma_f32_16x16x32_f16(a0l, bh, acc[0][ntl], 0, 0, 0);
                acc[0][ntl] = __builtin_amdgcn_mfma_f32_16x16x32_f16(a0h, bl, acc[0][ntl], 0, 0, 0);
                acc[1][ntl] = __builtin_amdgcn_mfma_f32_16x16x32_f16(a1h, bh, acc[1][ntl], 0, 0, 0);
                acc[1][ntl] = __builtin_amdgcn_mfma_f32_16x16x32_f16(a1l, bh, acc[1][ntl], 0, 0, 0);
                acc[1][ntl] = __builtin_amdgcn_mfma_f32_16x16x32_f16(a1h, bl, acc[1][ntl], 0, 0, 0);
            }
        }
        #pragma unroll
        for (int ntl = 0; ntl < 2; ++ntl) {
            int col = (nt0 + ntl) * 16 + (lane & 15);
            float bv = bol[col];
            #pragma unroll
            for (int mt = 0; mt < 2; ++mt) {
                #pragma unroll
                for (int r = 0; r < 4; ++r) {
                    int row = mt * 16 + (lane >> 4) * 4 + r;
                    out[((size_t)(m * kP + row)) * kDIM + col] = acc[mt][ntl][r] + bv;
                }
            }
        }
    }
}

//==========================================================================
// Fallback (ws too small): fused all-VALU kernel (round-2 design).
//==========================================================================
__global__ __launch_bounds__(TPB, 2)
void octree_attn_valu(const float* __restrict__ q_data,
                      const float* __restrict__ kv_data,
                      const int*   __restrict__ rel_pos,
                      const float* __restrict__ mask,
                      const float* __restrict__ Wq,  const float* __restrict__ bq,
                      const float* __restrict__ Wkv, const float* __restrict__ bkv,
                      const float* __restrict__ Wo,  const float* __restrict__ bo,
                      const float* __restrict__ rpe_table,
                      float* __restrict__ out)
{
    __shared__ float Qs [kP * 260];
    __shared__ float KVs[kP * 516];
    __shared__ float AOs[kP * 260];
    __shared__ float rpe_t[8 * 160];
    __shared__ int   rpl[kP * 100];
    __shared__ float mskl[kP * 36];

    const int m = blockIdx.x;
    const int tid = threadIdx.x;
    const int wave = tid >> 6;
    const int lane = tid & 63;

    {
        const float4* qsrc = reinterpret_cast<const float4*>(q_data  + (size_t)m * kP * kDIM);
        const float4* ksrc = reinterpret_cast<const float4*>(kv_data + (size_t)m * kP * kDIM);
        #pragma unroll
        for (int rep = 0; rep < 4; ++rep) {
            int f = tid + rep * TPB;
            int row = f >> 6;
            int c4 = (f & 63) << 2;
            *reinterpret_cast<float4*>(&Qs[row * 260 + c4]) = qsrc[f];
            *reinterpret_cast<float4*>(&AOs[row * 260 + c4]) = ksrc[f];
        }
        const int4* rsrc = reinterpret_cast<const int4*>(rel_pos + (size_t)m * kP * kP * 3);
        for (int f = tid; f < 768; f += TPB) {
            int row = f / 24;
            int w = f % 24;
            *reinterpret_cast<int4*>(&rpl[row * 100 + w * 4]) = rsrc[f];
        }
        const float4* msrc = reinterpret_cast<const float4*>(mask + (size_t)m * kP * kP);
        if (tid < 256) {
            int row = tid >> 3;
            int w = tid & 7;
            *reinterpret_cast<float4*>(&mskl[row * 36 + w * 4]) = msrc[tid];
        }
        for (int i = tid; i < 3 * kRPE * 8; i += TPB)
            rpe_t[(i & 7) * 160 + (i >> 3)] = rpe_table[i];
    }
    __syncthreads();

    float qacc[4][4];
    {
        #pragma unroll
        for (int i = 0; i < 4; ++i) {
            #pragma unroll
            for (int j = 0; j < 4; ++j) qacc[i][j] = 0.f;
        }
        const int r0 = wave * 4;
        const int c0 = lane * 4;
        #pragma unroll 4
        for (int k = 0; k < kDIM; ++k) {
            float a[4];
            #pragma unroll
            for (int i = 0; i < 4; ++i) a[i] = Qs[(r0 + i) * 260 + k];
            float b[4];
            *reinterpret_cast<float4*>(b) =
                *reinterpret_cast<const float4*>(&Wq[(size_t)k * kDIM + c0]);
            #pragma unroll
            for (int i = 0; i < 4; ++i) {
                #pragma unroll
                for (int j = 0; j < 4; ++j) qacc[i][j] = fmaf(a[i], b[j], qacc[i][j]);
            }
        }
    }
    __syncthreads();
    {
        const int r0 = wave * 4;
        const int c0 = lane * 4;
        float bv[4];
        *reinterpret_cast<float4*>(bv) = *reinterpret_cast<const float4*>(&bq[c0]);
        #pragma unroll
        for (int i = 0; i < 4; ++i) {
            float4 o;
            o.x = (qacc[i][0] + bv[0]) * kSCALE;
            o.y = (qacc[i][1] + bv[1]) * kSCALE;
            o.z = (qacc[i][2] + bv[2]) * kSCALE;
            o.w = (qacc[i][3] + bv[3]) * kSCALE;
            *reinterpret_cast<float4*>(&Qs[(r0 + i) * 260 + c0]) = o;
        }
    }
    {
        float kvacc[4][8];
        #pragma unroll
        for (int i = 0; i < 4; ++i) {
            #pragma unroll
            for (int j = 0; j < 8; ++j) kvacc[i][j] = 0.f;
        }
        const int r0 = wave * 4;
        const int c0 = lane * 8;
        #pragma unroll 2
        for (int k = 0; k < kDIM; ++k) {
            float a[4];
            #pragma unroll
            for (int i = 0; i < 4; ++i) a[i] = AOs[(r0 + i) * 260 + k];
            float b[8];
            *reinterpret_cast<float4*>(&b[0]) =
                *reinterpret_cast<const float4*>(&Wkv[(size_t)k * 512 + c0]);
            *reinterpret_cast<float4*>(&b[4]) =
                *reinterpret_cast<const float4*>(&Wkv[(size_t)k * 512 + c0 + 4]);
            #pragma unroll
            for (int i = 0; i < 4; ++i) {
                #pragma unroll
                for (int j = 0; j < 8; ++j) kvacc[i][j] = fmaf(a[i], b[j], kvacc[i][j]);
            }
        }
        float bv[8];
        *reinterpret_cast<float4*>(&bv[0]) = *reinterpret_cast<const float4*>(&bkv[c0]);
        *reinterpret_cast<float4*>(&bv[4]) = *reinterpret_cast<const float4*>(&bkv[c0 + 4]);
        #pragma unroll
        for (int i = 0; i < 4; ++i) {
            #pragma unroll
            for (int j = 0; j < 8; ++j)
                KVs[(r0 + i) * 516 + c0 + j] = kvacc[i][j] + bv[j];
        }
    }
    __syncthreads();
    {
        const int h = wave;
        const int ri = lane >> 3;
        const int ci = lane & 7;
        float s[4][4];
        #pragma unroll
        for (int i = 0; i < 4; ++i) {
            #pragma unroll
            for (int j = 0; j < 4; ++j) s[i][j] = 0.f;
        }
        #pragma unroll
        for (int db = 0; db < 8; ++db) {
            float4 qv[4], kv[4];
            #pragma unroll
            for (int i = 0; i < 4; ++i)
                qv[i] = *reinterpret_cast<const float4*>(&Qs[(ri + 8 * i) * 260 + h * 32 + db * 4]);
            #pragma unroll
            for (int j = 0; j < 4; ++j)
                kv[j] = *reinterpret_cast<const float4*>(&KVs[(ci + 8 * j) * 516 + h * 32 + db * 4]);
            #pragma unroll
            for (int i = 0; i < 4; ++i) {
                #pragma unroll
                for (int j = 0; j < 4; ++j) {
                    s[i][j] = fmaf(qv[i].x, kv[j].x, s[i][j]);
                    s[i][j] = fmaf(qv[i].y, kv[j].y, s[i][j]);
                    s[i][j] = fmaf(qv[i].z, kv[j].z, s[i][j]);
                    s[i][j] = fmaf(qv[i].w, kv[j].w, s[i][j]);
                }
            }
        }
        #pragma unroll
        for (int i = 0; i < 4; ++i) {
            #pragma unroll
            for (int j = 0; j < 4; ++j) {
                int r = ri + 8 * i;
                int c = ci + 8 * j;
                int base = r * 100 + c * 3;
                int p0 = min(max(rpl[base + 0], -kPOS), kPOS) + kPOS;
                int p1 = min(max(rpl[base + 1], -kPOS), kPOS) + kPOS + kRPE;
                int p2 = min(max(rpl[base + 2], -kPOS), kPOS) + kPOS + 2 * kRPE;
                s[i][j] += rpe_t[h * 160 + p0] + rpe_t[h * 160 + p1] + rpe_t[h * 160 + p2]
                         + mskl[r * 36 + c];
            }
        }
        #pragma unroll
        for (int i = 0; i < 4; ++i) {
            float mx = fmaxf(fmaxf(s[i][0], s[i][1]), fmaxf(s[i][2], s[i][3]));
            mx = fmaxf(mx, __shfl_xor(mx, 1));
            mx = fmaxf(mx, __shfl_xor(mx, 2));
            mx = fmaxf(mx, __shfl_xor(mx, 4));
            float e0 = __expf(s[i][0] - mx);
            float e1 = __expf(s[i][1] - mx);
            float e2 = __expf(s[i][2] - mx);
            float e3 = __expf(s[i][3] - mx);
            float sum = e0 + e1 + e2 + e3;
            sum += __shfl_xor(sum, 1);
            sum += __shfl_xor(sum, 2);
            sum += __shfl_xor(sum, 4);
            float inv = 1.0f / sum;
            s[i][0] = e0 * inv;
            s[i][1] = e1 * inv;
            s[i][2] = e2 * inv;
            s[i][3] = e3 * inv;
        }
        #pragma unroll
        for (int i = 0; i < 4; ++i) {
            #pragma unroll
            for (int j = 0; j < 4; ++j)
                Qs[(ri + 8 * i) * 260 + h * 32 + ci + 8 * j] = s[i][j];
        }
        __syncthreads();
        float o[4][4];
        #pragma unroll
        for (int i = 0; i < 4; ++i) {
            #pragma unroll
            for (int j = 0; j < 4; ++j) o[i][j] = 0.f;
        }
        #pragma unroll 4
        for (int c = 0; c < kP; ++c) {
            float pv[4], vv[4];
            #pragma unroll
            for (int i = 0; i < 4; ++i) pv[i] = Qs[(ri + 8 * i) * 260 + h * 32 + c];
            #pragma unroll
            for (int j = 0; j < 4; ++j) vv[j] = KVs[c * 516 + 256 + h * 32 + ci + 8 * j];
            #pragma unroll
            for (int i = 0; i < 4; ++i) {
                #pragma unroll
                for (int j = 0; j < 4; ++j) o[i][j] = fmaf(pv[i], vv[j], o[i][j]);
            }
        }
        #pragma unroll
        for (int i = 0; i < 4; ++i) {
            #pragma unroll
            for (int j = 0; j < 4; ++j)
                AOs[(ri + 8 * i) * 260 + h * 32 + ci + 8 * j] = o[i][j];
        }
    }
    __syncthreads();
    {
        float oacc[4][4];
        #pragma unroll
        for (int i = 0; i < 4; ++i) {
            #pragma unroll
            for (int j = 0; j < 4; ++j) oacc[i][j] = 0.f;
        }
        const int r0 = wave * 4;
        const int c0 = lane * 4;
        #pragma unroll 4
        for (int k = 0; k < kDIM; ++k) {
            float a[4];
            #pragma unroll
            for (int i = 0; i < 4; ++i) a[i] = AOs[(r0 + i) * 260 + k];
            float b[4];
            *reinterpret_cast<float4*>(b) =
                *reinterpret_cast<const float4*>(&Wo[(size_t)k * kDIM + c0]);
            #pragma unroll
            for (int i = 0; i < 4; ++i) {
                #pragma unroll
                for (int j = 0; j < 4; ++j) oacc[i][j] = fmaf(a[i], b[j], oacc[i][j]);
            }
        }
        float bv[4];
        *reinterpret_cast<float4*>(bv) = *reinterpret_cast<const float4*>(&bo[c0]);
        #pragma unroll
        for (int i = 0; i < 4; ++i) {
            float4 o;
            o.x = oacc[i][0] + bv[0];
            o.y = oacc[i][1] + bv[1];
            o.z = oacc[i][2] + bv[2];
            o.w = oacc[i][3] + bv[3];
            *reinterpret_cast<float4*>(&out[((size_t)(m * kP + r0 + i)) * kDIM + c0]) = o;
        }
    }
}

extern "C" void kernel_launch(void* const* d_in, const int* in_sizes, int n_in,
                              void* d_out, int out_size, void* d_ws, size_t ws_size,
                              hipStream_t stream)
{
    const float* q_data  = (const float*)d_in[0];
    const float* kv_data = (const float*)d_in[1];
    const int*   rel_pos = (const int*)  d_in[2];
    const float* mask    = (const float*)d_in[3];
    const float* Wq      = (const float*)d_in[4];
    const float* bq      = (const float*)d_in[5];
    const float* Wkv     = (const float*)d_in[6];
    const float* bkv     = (const float*)d_in[7];
    const float* Wo      = (const float*)d_in[8];
    const float* bo      = (const float*)d_in[9];
    const float* rpe     = (const float*)d_in[10];
    float* outp = (float*)d_out;
    const int M = in_sizes[0] / (kDIM * kP);   // 4096 patches

    if (ws_size >= WS_NEED_BYTES) {
        hipLaunchKernelGGL(pack_weights, dim3(128), dim3(256), 0, stream,
                           Wq, Wkv, Wo, (_Float16*)d_ws);
        hipLaunchKernelGGL(octree_attn_mfma, dim3(M), dim3(TPB), 0, stream,
                           q_data, kv_data, rel_pos, mask, bq, bkv, bo, rpe,
                           (const _Float16*)d_ws, outp);
    } else {
        hipLaunchKernelGGL(octree_attn_valu, dim3(M), dim3(TPB), 0, stream,
                           q_data, kv_data, rel_pos, mask, Wq, bq, Wkv, bkv, Wo, bo,
                           rpe, outp);
    }
}

// Round 5
// 625.826 us; speedup vs baseline: 1.1760x; 1.1760x over previous
//
#include <hip/hip_runtime.h>
#include <hip/hip_bf16.h>

#define TPB 512

typedef _Float16 half8 __attribute__((ext_vector_type(8)));
typedef float    f32x4 __attribute__((ext_vector_type(4)));

constexpr int kDIM   = 256;
constexpr int kP     = 32;   // patch size
constexpr int kPOS   = 25;
constexpr int kRPE   = 51;
constexpr float kSCALE = 0.17677669529663687f; // 32^-0.5

// ---- d_ws packed-weight layout (in _Float16 units) ----
constexpr size_t WQ_HI  = 0;        // 65536 halves (16nt * 8k0 * 64 * 8)
constexpr size_t WQ_LO  = 65536;
constexpr size_t WKV_HI = 131072;   // 131072 halves (32nt * 8k0 * 64 * 8)
constexpr size_t WKV_LO = 262144;
constexpr size_t WO_HI  = 393216;   // 65536 halves
constexpr size_t WO_LO  = 458752;

// ---- LDS arena (bytes) ----
// R_A [0,33280):      XqF hi/lo (32K) -> Q fp32 [32][260] -> P in head cols -> AOF hi/lo
// R_B [33280,67072):  XkvF hi/lo (32K) -> Kh fp16 [32][264] + Vh fp16 [32][264]
// tables [67072,79872): rpl8 u8[32][100], msk f32[32][36], rpe_t f32[8][156]
constexpr int ARENA_BYTES = 79872;   // 2 blocks/CU (<= 81920)

//==========================================================================
// Weight pack: W (row-major [K][C]) -> fragment-linear fp16 hi/lo.
// B-frag for tile (nt,k0), lane l, elem j = W[k0*32 + (l>>4)*8 + j][nt*16 + (l&15)]
// stored at dst[((nt*8+k0)*64 + l)*8 + j].
//==========================================================================
__global__ void pack_weights(const float* __restrict__ Wq,
                             const float* __restrict__ Wkv,
                             const float* __restrict__ Wo,
                             _Float16* __restrict__ ws)
{
    int T = blockIdx.x * 256 + threadIdx.x;   // 0..32767
    const float* W;
    _Float16* dh;
    _Float16* dl;
    int C, i;
    if (T < 8192) {
        W = Wq;  C = 256; i = T;         dh = ws + WQ_HI;  dl = ws + WQ_LO;
    } else if (T < 24576) {
        W = Wkv; C = 512; i = T - 8192;  dh = ws + WKV_HI; dl = ws + WKV_LO;
    } else {
        W = Wo;  C = 256; i = T - 24576; dh = ws + WO_HI;  dl = ws + WO_LO;
    }
    int nt = i >> 9;
    int k0 = (i >> 6) & 7;
    int l  = i & 63;
    int kb = k0 * 32 + ((l >> 4) << 3);
    int n  = nt * 16 + (l & 15);
    half8 H, L;
    #pragma unroll
    for (int j = 0; j < 8; ++j) {
        float w = W[(size_t)(kb + j) * C + n];
        _Float16 h = (_Float16)w;
        H[j] = h;
        L[j] = (_Float16)(w - (float)h);
    }
    *reinterpret_cast<half8*>(dh + (size_t)i * 8) = H;
    *reinterpret_cast<half8*>(dl + (size_t)i * 8) = L;
}

//==========================================================================
// Fused per-patch kernel: MFMA projections + fp32 VALU attention.
// 2 blocks/CU (LDS 79,872 B).
//==========================================================================
__global__ __launch_bounds__(TPB, 4)
void octree_attn_mfma(const float* __restrict__ q_data,
                      const float* __restrict__ kv_data,
                      const int*   __restrict__ rel_pos,
                      const float* __restrict__ mask,
                      const float* __restrict__ bq,
                      const float* __restrict__ bkv,
                      const float* __restrict__ bo,
                      const float* __restrict__ rpe_table,
                      const _Float16* __restrict__ wsh,
                      float* __restrict__ out)
{
    __shared__ __align__(16) char arena[ARENA_BYTES];
    _Float16* XqF_hi  = (_Float16*)(arena);             // [0,16384)
    _Float16* XqF_lo  = (_Float16*)(arena + 16384);     // [16384,32768)
    float*    Qs      = (float*)   (arena);             // [32][260] overlays XqF
    _Float16* AOF_hi  = (_Float16*)(arena);             // overlays Qs/P after PV
    _Float16* AOF_lo  = (_Float16*)(arena + 16384);
    _Float16* XkvF_hi = (_Float16*)(arena + 33280);     // [33280,49664)
    _Float16* XkvF_lo = (_Float16*)(arena + 49664);     // [49664,66048)
    _Float16* Kh      = (_Float16*)(arena + 33280);     // [32][264] overlays XkvF
    _Float16* Vh      = (_Float16*)(arena + 50176);     // [32][264]
    unsigned char* rpl8 = (unsigned char*)(arena + 67072); // [32][100]
    float*    msk     = (float*)   (arena + 70272);     // [32][36]
    float*    rpe_t   = (float*)   (arena + 74880);     // [8][156]

    const int m    = blockIdx.x;
    const int tid  = threadIdx.x;
    const int wave = tid >> 6;
    const int lane = tid & 63;

    //---------------- stage: frag-slot-linear (conflict-free LDS writes) ------
    {
        const float* qsrc = q_data  + (size_t)m * kP * kDIM;
        const float* ksrc = kv_data + (size_t)m * kP * kDIM;
        #pragma unroll
        for (int rep = 0; rep < 2; ++rep) {
            int s   = tid + rep * TPB;          // frag slot 0..1023
            int mt  = s >> 9;
            int k0  = (s >> 6) & 7;
            int l   = s & 63;
            int row = mt * 16 + (l & 15);
            int col = k0 * 32 + ((l >> 4) << 3);
            const float* qp = qsrc + row * kDIM + col;
            float4 x0 = *reinterpret_cast<const float4*>(qp);
            float4 x1 = *reinterpret_cast<const float4*>(qp + 4);
            float xs[8] = {x0.x, x0.y, x0.z, x0.w, x1.x, x1.y, x1.z, x1.w};
            half8 H, L;
            #pragma unroll
            for (int j = 0; j < 8; ++j) {
                _Float16 h = (_Float16)xs[j];
                H[j] = h;
                L[j] = (_Float16)(xs[j] - (float)h);
            }
            *reinterpret_cast<half8*>(XqF_hi + s * 8) = H;
            *reinterpret_cast<half8*>(XqF_lo + s * 8) = L;
            const float* kp = ksrc + row * kDIM + col;
            float4 y0 = *reinterpret_cast<const float4*>(kp);
            float4 y1 = *reinterpret_cast<const float4*>(kp + 4);
            float ys[8] = {y0.x, y0.y, y0.z, y0.w, y1.x, y1.y, y1.z, y1.w};
            #pragma unroll
            for (int j = 0; j < 8; ++j) {
                _Float16 h = (_Float16)ys[j];
                H[j] = h;
                L[j] = (_Float16)(ys[j] - (float)h);
            }
            *reinterpret_cast<half8*>(XkvF_hi + s * 8) = H;
            *reinterpret_cast<half8*>(XkvF_lo + s * 8) = L;
        }
        // rel_pos -> clamped u8 (value+25 in 0..50)
        const int4* rsrc = reinterpret_cast<const int4*>(rel_pos + (size_t)m * kP * kP * 3);
        for (int f = tid; f < 768; f += TPB) {
            int4 v = rsrc[f];
            int idx = f * 4;
            int row = idx / 96;
            int col = idx % 96;
            uchar4 pk;
            pk.x = (unsigned char)(min(max(v.x, -kPOS), kPOS) + kPOS);
            pk.y = (unsigned char)(min(max(v.y, -kPOS), kPOS) + kPOS);
            pk.z = (unsigned char)(min(max(v.z, -kPOS), kPOS) + kPOS);
            pk.w = (unsigned char)(min(max(v.w, -kPOS), kPOS) + kPOS);
            *reinterpret_cast<uchar4*>(rpl8 + row * 100 + col) = pk;
        }
        const float4* msrc = reinterpret_cast<const float4*>(mask + (size_t)m * kP * kP);
        if (tid < 256) {
            int row = tid >> 3;
            int w   = tid & 7;
            *reinterpret_cast<float4*>(&msk[row * 36 + w * 4]) = msrc[tid];
        }
        for (int i = tid; i < 3 * kRPE * 8; i += TPB) {
            int idx = i >> 3;
            int h   = i & 7;                    // rpe_table (153,8) row-major
            rpe_t[h * 156 + idx] = rpe_table[i];
        }
    }
    __syncthreads();

    //---------------- merged projections (MFMA, accumulate in regs) -----------
    // KV: wave owns nt 4w..4w+3 (of 32).  Q: wave owns nt 2w..2w+1 (of 16).
    f32x4 akv[2][4];
    f32x4 aq[2][2];
    {
        #pragma unroll
        for (int a = 0; a < 2; ++a) {
            #pragma unroll
            for (int b = 0; b < 4; ++b) akv[a][b] = f32x4{0.f, 0.f, 0.f, 0.f};
            #pragma unroll
            for (int b = 0; b < 2; ++b) aq[a][b] = f32x4{0.f, 0.f, 0.f, 0.f};
        }
        const _Float16* BKh = wsh + WKV_HI;
        const _Float16* BKl = wsh + WKV_LO;
        const _Float16* BQh = wsh + WQ_HI;
        const _Float16* BQl = wsh + WQ_LO;
        const int ntkv = wave * 4;
        const int ntq  = wave * 2;
        #pragma unroll
        for (int k0 = 0; k0 < 8; ++k0) {
            half8 kv0h = *reinterpret_cast<const half8*>(XkvF_hi + (k0 * 64 + lane) * 8);
            half8 kv0l = *reinterpret_cast<const half8*>(XkvF_lo + (k0 * 64 + lane) * 8);
            half8 kv1h = *reinterpret_cast<const half8*>(XkvF_hi + ((8 + k0) * 64 + lane) * 8);
            half8 kv1l = *reinterpret_cast<const half8*>(XkvF_lo + ((8 + k0) * 64 + lane) * 8);
            #pragma unroll
            for (int ntl = 0; ntl < 4; ++ntl) {
                int nt = ntkv + ntl;
                half8 bh = *reinterpret_cast<const half8*>(BKh + ((size_t)(nt * 8 + k0) * 64 + lane) * 8);
                half8 bl = *reinterpret_cast<const half8*>(BKl + ((size_t)(nt * 8 + k0) * 64 + lane) * 8);
                akv[0][ntl] = __builtin_amdgcn_mfma_f32_16x16x32_f16(kv0h, bh, akv[0][ntl], 0, 0, 0);
                akv[0][ntl] = __builtin_amdgcn_mfma_f32_16x16x32_f16(kv0l, bh, akv[0][ntl], 0, 0, 0);
                akv[0][ntl] = __builtin_amdgcn_mfma_f32_16x16x32_f16(kv0h, bl, akv[0][ntl], 0, 0, 0);
                akv[1][ntl] = __builtin_amdgcn_mfma_f32_16x16x32_f16(kv1h, bh, akv[1][ntl], 0, 0, 0);
                akv[1][ntl] = __builtin_amdgcn_mfma_f32_16x16x32_f16(kv1l, bh, akv[1][ntl], 0, 0, 0);
                akv[1][ntl] = __builtin_amdgcn_mfma_f32_16x16x32_f16(kv1h, bl, akv[1][ntl], 0, 0, 0);
            }
            half8 q0h = *reinterpret_cast<const half8*>(XqF_hi + (k0 * 64 + lane) * 8);
            half8 q0l = *reinterpret_cast<const half8*>(XqF_lo + (k0 * 64 + lane) * 8);
            half8 q1h = *reinterpret_cast<const half8*>(XqF_hi + ((8 + k0) * 64 + lane) * 8);
            half8 q1l = *reinterpret_cast<const half8*>(XqF_lo + ((8 + k0) * 64 + lane) * 8);
            #pragma unroll
            for (int ntl = 0; ntl < 2; ++ntl) {
                int nt = ntq + ntl;
                half8 bh = *reinterpret_cast<const half8*>(BQh + ((size_t)(nt * 8 + k0) * 64 + lane) * 8);
                half8 bl = *reinterpret_cast<const half8*>(BQl + ((size_t)(nt * 8 + k0) * 64 + lane) * 8);
                aq[0][ntl] = __builtin_amdgcn_mfma_f32_16x16x32_f16(q0h, bh, aq[0][ntl], 0, 0, 0);
                aq[0][ntl] = __builtin_amdgcn_mfma_f32_16x16x32_f16(q0l, bh, aq[0][ntl], 0, 0, 0);
                aq[0][ntl] = __builtin_amdgcn_mfma_f32_16x16x32_f16(q0h, bl, aq[0][ntl], 0, 0, 0);
                aq[1][ntl] = __builtin_amdgcn_mfma_f32_16x16x32_f16(q1h, bh, aq[1][ntl], 0, 0, 0);
                aq[1][ntl] = __builtin_amdgcn_mfma_f32_16x16x32_f16(q1l, bh, aq[1][ntl], 0, 0, 0);
                aq[1][ntl] = __builtin_amdgcn_mfma_f32_16x16x32_f16(q1h, bl, aq[1][ntl], 0, 0, 0);
            }
        }
    }
    __syncthreads();   // all frag reads done -> overlay regions

    //---------------- epilogues: K/V fp16, Q fp32 (biases from global) --------
    {
        #pragma unroll
        for (int ntl = 0; ntl < 4; ++ntl) {
            int cg = (wave * 4 + ntl) * 16 + (lane & 15);   // 0..511
            float bv = bkv[cg];
            #pragma unroll
            for (int mt = 0; mt < 2; ++mt) {
                #pragma unroll
                for (int r = 0; r < 4; ++r) {
                    int row = mt * 16 + (lane >> 4) * 4 + r;
                    _Float16 v = (_Float16)(akv[mt][ntl][r] + bv);
                    if (cg < 256) Kh[row * 264 + cg] = v;
                    else          Vh[row * 264 + (cg - 256)] = v;
                }
            }
        }
        #pragma unroll
        for (int ntl = 0; ntl < 2; ++ntl) {
            int col = (wave * 2 + ntl) * 16 + (lane & 15);  // 0..255
            float bv = bq[col];
            #pragma unroll
            for (int mt = 0; mt < 2; ++mt) {
                #pragma unroll
                for (int r = 0; r < 4; ++r) {
                    int row = mt * 16 + (lane >> 4) * 4 + r;
                    Qs[row * 260 + col] = (aq[mt][ntl][r] + bv) * kSCALE;
                }
            }
        }
    }
    __syncthreads();   // Q, K, V ready

    //---------------- attention (fp32 VALU, K/V fp16): one wave per head ------
    {
        const int h  = wave;
        const int ri = lane >> 3;   // rows ri + 8i
        const int ci = lane & 7;    // cols ci + 8j
        float s[4][4];
        #pragma unroll
        for (int i = 0; i < 4; ++i) {
            #pragma unroll
            for (int j = 0; j < 4; ++j) s[i][j] = 0.f;
        }

        #pragma unroll
        for (int db = 0; db < 4; ++db) {        // 8 hd elems per iter
            float kf[4][8];
            #pragma unroll
            for (int j = 0; j < 4; ++j) {
                half8 k8 = *reinterpret_cast<const half8*>(
                    &Kh[(ci + 8 * j) * 264 + h * 32 + db * 8]);
                #pragma unroll
                for (int e = 0; e < 8; ++e) kf[j][e] = (float)k8[e];
            }
            #pragma unroll
            for (int i = 0; i < 4; ++i) {
                float4 qa = *reinterpret_cast<const float4*>(
                    &Qs[(ri + 8 * i) * 260 + h * 32 + db * 8]);
                float4 qb = *reinterpret_cast<const float4*>(
                    &Qs[(ri + 8 * i) * 260 + h * 32 + db * 8 + 4]);
                float qf[8] = {qa.x, qa.y, qa.z, qa.w, qb.x, qb.y, qb.z, qb.w};
                #pragma unroll
                for (int j = 0; j < 4; ++j) {
                    #pragma unroll
                    for (int e = 0; e < 8; ++e)
                        s[i][j] = fmaf(qf[e], kf[j][e], s[i][j]);
                }
            }
        }

        // rpe bias (u8-staged) + mask
        #pragma unroll
        for (int i = 0; i < 4; ++i) {
            #pragma unroll
            for (int j = 0; j < 4; ++j) {
                int r = ri + 8 * i;
                int c = ci + 8 * j;
                int base = r * 100 + c * 3;
                int p0 = rpl8[base + 0];
                int p1 = rpl8[base + 1];
                int p2 = rpl8[base + 2];
                float bias = rpe_t[h * 156 + p0]
                           + rpe_t[h * 156 + 51 + p1]
                           + rpe_t[h * 156 + 102 + p2];
                s[i][j] += bias + msk[r * 36 + c];
            }
        }

        // softmax over 32 cols (4 regs x 8 ci-lanes)
        #pragma unroll
        for (int i = 0; i < 4; ++i) {
            float mx = fmaxf(fmaxf(s[i][0], s[i][1]), fmaxf(s[i][2], s[i][3]));
            mx = fmaxf(mx, __shfl_xor(mx, 1));
            mx = fmaxf(mx, __shfl_xor(mx, 2));
            mx = fmaxf(mx, __shfl_xor(mx, 4));
            float e0 = __expf(s[i][0] - mx);
            float e1 = __expf(s[i][1] - mx);
            float e2 = __expf(s[i][2] - mx);
            float e3 = __expf(s[i][3] - mx);
            float sum = e0 + e1 + e2 + e3;
            sum += __shfl_xor(sum, 1);
            sum += __shfl_xor(sum, 2);
            sum += __shfl_xor(sum, 4);
            float inv = 1.0f / sum;
            s[i][0] = e0 * inv;
            s[i][1] = e1 * inv;
            s[i][2] = e2 * inv;
            s[i][3] = e3 * inv;
        }

        // P -> this head's own (now dead) Q columns
        #pragma unroll
        for (int i = 0; i < 4; ++i) {
            #pragma unroll
            for (int j = 0; j < 4; ++j)
                Qs[(ri + 8 * i) * 260 + h * 32 + ci + 8 * j] = s[i][j];
        }
        __syncthreads();

        // PV (V fp16, cvt on the fly)
        float o[4][4];
        #pragma unroll
        for (int i = 0; i < 4; ++i) {
            #pragma unroll
            for (int j = 0; j < 4; ++j) o[i][j] = 0.f;
        }
        #pragma unroll 4
        for (int c = 0; c < kP; ++c) {
            float pv[4], vv[4];
            #pragma unroll
            for (int i = 0; i < 4; ++i)
                pv[i] = Qs[(ri + 8 * i) * 260 + h * 32 + c];
            #pragma unroll
            for (int j = 0; j < 4; ++j)
                vv[j] = (float)Vh[c * 264 + h * 32 + ci + 8 * j];
            #pragma unroll
            for (int i = 0; i < 4; ++i) {
                #pragma unroll
                for (int j = 0; j < 4; ++j)
                    o[i][j] = fmaf(pv[i], vv[j], o[i][j]);
            }
        }
        __syncthreads();   // all P reads done -> R_A becomes AOF

        // write attention output directly as O-proj A-frags (hi/lo)
        #pragma unroll
        for (int i = 0; i < 4; ++i) {
            int row = ri + 8 * i;
            int mt  = row >> 4;
            #pragma unroll
            for (int j = 0; j < 4; ++j) {
                int offv = ((mt * 8 + h) * 64 + ((j << 4) | (row & 15))) * 8 + ci;
                float val = o[i][j];
                _Float16 hh = (_Float16)val;
                AOF_hi[offv] = hh;
                AOF_lo[offv] = (_Float16)(val - (float)hh);
            }
        }
    }
    __syncthreads();   // AOF complete

    //---------------- output projection (MFMA): out = AO @ Wo + bo ------------
    {
        const _Float16* Bh = wsh + WO_HI;
        const _Float16* Bl = wsh + WO_LO;
        const int nt0 = wave * 2;
        f32x4 acc[2][2];
        #pragma unroll
        for (int a = 0; a < 2; ++a) {
            #pragma unroll
            for (int b = 0; b < 2; ++b) acc[a][b] = f32x4{0.f, 0.f, 0.f, 0.f};
        }
        #pragma unroll
        for (int k0 = 0; k0 < 8; ++k0) {
            half8 a0h = *reinterpret_cast<const half8*>(AOF_hi + (k0 * 64 + lane) * 8);
            half8 a0l = *reinterpret_cast<const half8*>(AOF_lo + (k0 * 64 + lane) * 8);
            half8 a1h = *reinterpret_cast<const half8*>(AOF_hi + ((8 + k0) * 64 + lane) * 8);
            half8 a1l = *reinterpret_cast<const half8*>(AOF_lo + ((8 + k0) * 64 + lane) * 8);
            #pragma unroll
            for (int ntl = 0; ntl < 2; ++ntl) {
                int nt = nt0 + ntl;
                half8 bh = *reinterpret_cast<const half8*>(Bh + ((size_t)(nt * 8 + k0) * 64 + lane) * 8);
                half8 bl = *reinterpret_cast<const half8*>(Bl + ((size_t)(nt * 8 + k0) * 64 + lane) * 8);
                acc[0][ntl] = __builtin_amdgcn_mfma_f32_16x16x32_f16(a0h, bh, acc[0][ntl], 0, 0, 0);
                acc[0][ntl] = __builtin_amdgcn_mfma_f32_16x16x32_f16(a0l, bh, acc[0][ntl], 0, 0, 0);
                acc[0][ntl] = __builtin_amdgcn_mfma_f32_16x16x32_f16(a0h, bl, acc[0][ntl], 0, 0, 0);
                acc[1][ntl] = __builtin_amdgcn_mfma_f32_16x16x32_f16(a1h, bh, acc[1][ntl], 0, 0, 0);
                acc[1][ntl] = __builtin_amdgcn_mfma_f32_16x16x32_f16(a1l, bh, acc[1][ntl], 0, 0, 0);
                acc[1][ntl] = __builtin_amdgcn_mfma_f32_16x16x32_f16(a1h, bl, acc[1][ntl], 0, 0, 0);
            }
        }
        #pragma unroll
        for (int ntl = 0; ntl < 2; ++ntl) {
            int col = (nt0 + ntl) * 16 + (lane & 15);
            float bv = bo[col];
            #pragma unroll
            for (int mt = 0; mt < 2; ++mt) {
                #pragma unroll
                for (int r = 0; r < 4; ++r) {
                    int row = mt * 16 + (lane >> 4) * 4 + r;
                    out[((size_t)(m * kP + row)) * kDIM + col] = acc[mt][ntl][r] + bv;
                }
            }
        }
    }
}

extern "C" void kernel_launch(void* const* d_in, const int* in_sizes, int n_in,
                              void* d_out, int out_size, void* d_ws, size_t ws_size,
                              hipStream_t stream)
{
    const float* q_data  = (const float*)d_in[0];
    const float* kv_data = (const float*)d_in[1];
    const int*   rel_pos = (const int*)  d_in[2];
    const float* mask    = (const float*)d_in[3];
    const float* Wq      = (const float*)d_in[4];
    const float* bq      = (const float*)d_in[5];
    const float* Wkv     = (const float*)d_in[6];
    const float* bkv     = (const float*)d_in[7];
    const float* Wo      = (const float*)d_in[8];
    const float* bo      = (const float*)d_in[9];
    const float* rpe     = (const float*)d_in[10];
    float* outp = (float*)d_out;
    const int M = in_sizes[0] / (kDIM * kP);   // 4096 patches

    hipLaunchKernelGGL(pack_weights, dim3(128), dim3(256), 0, stream,
                       Wq, Wkv, Wo, (_Float16*)d_ws);
    hipLaunchKernelGGL(octree_attn_mfma, dim3(M), dim3(TPB), 0, stream,
                       q_data, kv_data, rel_pos, mask, bq, bkv, bo, rpe,
                       (const _Float16*)d_ws, outp);
}